// Round 1
// 295.474 us; speedup vs baseline: 1.0262x; 1.0262x over previous
//
#include <hip/hip_runtime.h>

// VQ-VAE codebook quantization, MI355X (gfx950)
// z: [32, 256, 32, 32] fp32 ; codebook: [1024, 256] fp32
// outputs (concat fp32): z_q [32,256,32,32] (8388608) | idx [32768] | loss [1]
//
// Correctness contract: idx must match numpy's fp32 argmin of
//   dist = fl( fl(znorm + enorm) - 2*dot ),  ties -> lowest index.
// The +znorm(~256) term quantizes dist to ulp ~1.5e-5; replicating that
// quantization (NOT dropping the constant term) is what makes ties match.
//
// R1 changes vs 303us baseline:
//  - e-read lane ownership remapped to {tx*4..+3} u {128+tx*4..+3}: both
//    inner-loop ds_read_b128 are contiguous across the half-wave ->
//    conflict-free (was 32B lane stride -> multiway conflict, 2.3e7 PMC).
//  - Es double-buffered at BK=8 (same 16KB), async-split staging:
//    gload->regs issued before compute, LDS write after, ONE barrier/step.
//    Staging writes (kk=t>>1) now 2 lanes/bank = conflict-free.

#define D_DIM   256
#define K_CODES 1024
#define HW      1024
#define MT      128     // positions per block
#define NT      256     // codes per N-chunk
#define BK      8       // d-rows per Es buffer (double-buffered)
#define THREADS 512
#define NSTEP   128     // 4 chunks * 32 steps

#define ZQ_OFF   0
#define IDX_OFF  8388608
#define LOSS_OFF 8421376

// As[256][128] + Es[2][8][256] + bestm[128] + znorm_s[128]
#define SMEM_FLOATS (D_DIM*MT + 2*BK*NT + MT + MT)   // 32768+4096+128+128 = 37120
#define SMEM_BYTES  (SMEM_FLOATS * 4)                // 148480 B < 160 KiB/CU

extern __shared__ float smem[];

// ws: enorm[k] = fp32 sum of cb[k][d]^2 (own order; ~ulp(8e-5) agreement is enough)
__global__ void enorm_kernel(const float* __restrict__ cb, float* __restrict__ enorm) {
    int gt = blockIdx.x * blockDim.x + threadIdx.x;
    int k = gt >> 6;
    int lane = gt & 63;
    const float4* row = (const float4*)(cb + (size_t)k * D_DIM);
    float4 v = row[lane];
    float s = fmaf(v.x, v.x, fmaf(v.y, v.y, fmaf(v.z, v.z, v.w * v.w)));
    #pragma unroll
    for (int off = 32; off; off >>= 1) s += __shfl_xor(s, off);
    if (lane == 0) enorm[k] = s;
}

__global__ __launch_bounds__(THREADS, 2) void vq_kernel(
        const float* __restrict__ z, const float* __restrict__ cb,
        const float* __restrict__ enorm, float* __restrict__ out)
{
    float* As = smem;                                       // [256][128]
    float* Es = smem + D_DIM * MT;                          // [2][BK][256]
    int*   bestm   = (int*)(smem + D_DIM*MT + 2*BK*NT);     // [128]
    float* znorm_s = (float*)(smem + D_DIM*MT + 2*BK*NT + MT); // [128]

    const int t   = threadIdx.x;
    const int blk = blockIdx.x;          // 256 blocks = 1/CU
    const int b   = blk >> 3;
    const int p0  = (blk & 7) * MT;
    const float* zb = z + (size_t)b * D_DIM * HW;

    // ---- stage A^T [256][128] (z read from HBM once, coalesced float4) ----
    for (int i = t; i < D_DIM * MT / 4; i += THREADS) {
        int d = i >> 5, m4 = i & 31;
        *(float4*)(As + d * MT + m4 * 4) = *(const float4*)(zb + d * HW + p0 + m4 * 4);
    }
    __syncthreads();

    // ---- znorm[m] = fp64 sum of As[:,m]^2, rounded to fp32 ----
    // (fp64 vs numpy's pairwise-fp32 differs by <=1-2 ulp of ~256; that's a
    //  uniform exact-ulp shift per row -> argmin invariant.)
    {
        int m = t & (MT - 1), q = t >> 7;            // 4 quarters of d
        const float* col = As + m;
        double zp = 0.0;
        #pragma unroll 8
        for (int d = q * 64; d < q * 64 + 64; ++d) {
            double v = (double)col[d * MT];
            zp += v * v;
        }
        double* zscr = (double*)Es;                  // 512 doubles = 4 KB scratch
        zscr[q * MT + m] = zp;
    }
    __syncthreads();
    if (t < MT) {
        double* zscr = (double*)Es;
        double s = (zscr[t] + zscr[MT + t]) + (zscr[2 * MT + t] + zscr[3 * MT + t]);
        znorm_s[t] = (float)s;
    }
    __syncthreads();

    const int tx = t & 31, ty = t >> 5;
    const int m_base = ty * 8;           // 16 ty-groups x 8 = 128 positions
    const int kx4 = tx * 4;              // codes kx4..+3 and 128+kx4..+3 per chunk

    float znf[8];
    #pragma unroll
    for (int i = 0; i < 8; ++i) znf[i] = znorm_s[m_base + i];

    float bestv[8]; int besti[8];
    #pragma unroll
    for (int i = 0; i < 8; ++i) { bestv[i] = 3.4e38f; besti[i] = 0; }

    // staging assignment: thread t -> row kk = t>>1 of the 256-code chunk,
    // float4 column half sd4 = t&1. One float4 per thread per step.
    const int skk = t >> 1, sd4 = t & 1;
    const float* cbp = cb + (size_t)skk * D_DIM + sd4 * 4;

    // ---- prologue: stage step g=0 (chunk 0, dk 0) into buffer 0 ----
    {
        float4 v = *(const float4*)(cbp);
        Es[(sd4 * 4 + 0) * NT + skk] = v.x;
        Es[(sd4 * 4 + 1) * NT + skk] = v.y;
        Es[(sd4 * 4 + 2) * NT + skk] = v.z;
        Es[(sd4 * 4 + 3) * NT + skk] = v.w;
    }
    __syncthreads();

    int cur = 0;
    for (int c = 0; c < 4; ++c) {
        const int k0 = c * NT;
        float acc[8][8];
        #pragma unroll
        for (int i = 0; i < 8; ++i)
            #pragma unroll
            for (int j = 0; j < 8; ++j) acc[i][j] = 0.f;

        for (int s = 0; s < 32; ++s) {
            const int g = c * 32 + s;
            const bool more = (g + 1 < NSTEP);
            // issue next-step global load early (latency hides under FMAs)
            float4 sv;
            if (more) {
                const int gn = g + 1;
                // addr = cb[( (gn>>5)*256 + skk )*256 + (gn&31)*8 + sd4*4]
                sv = *(const float4*)(cbp + (((size_t)(gn >> 5)) << 16) + ((gn & 31) << 3));
            }

            const float* Ec = Es + cur * (BK * NT);
            const int dk = s * BK;
            #pragma unroll
            for (int dd = 0; dd < BK; ++dd) {
                float a[8], e[8];
                *(float4*)(a)     = *(const float4*)(As + (dk + dd) * MT + m_base);
                *(float4*)(a + 4) = *(const float4*)(As + (dk + dd) * MT + m_base + 4);
                *(float4*)(e)     = *(const float4*)(Ec + dd * NT + kx4);        // codes kx4..+3
                *(float4*)(e + 4) = *(const float4*)(Ec + dd * NT + 128 + kx4);  // codes 128+kx4..+3
                #pragma unroll
                for (int i = 0; i < 8; ++i)
                    #pragma unroll
                    for (int j = 0; j < 8; ++j)
                        acc[i][j] = fmaf(a[i], e[j], acc[i][j]);
            }

            // write staged tile into the other buffer (after compute)
            if (more) {
                float* En = Es + (cur ^ 1) * (BK * NT);
                En[(sd4 * 4 + 0) * NT + skk] = sv.x;
                En[(sd4 * 4 + 1) * NT + skk] = sv.y;
                En[(sd4 * 4 + 2) * NT + skk] = sv.z;
                En[(sd4 * 4 + 3) * NT + skk] = sv.w;
            }
            __syncthreads();
            cur ^= 1;
        }

        // chunk epilogue: dist = fl( fl(znorm + enorm) - 2*dot ), np-style
        // lane's j=0..3 -> codes k0+kx4+j ; j=4..7 -> codes k0+128+kx4+(j-4)
        #pragma unroll
        for (int j = 0; j < 8; ++j) {
            const int kidx = k0 + ((j < 4) ? (kx4 + j) : (124 + kx4 + j));
            const float bn = enorm[kidx];
            #pragma unroll
            for (int i = 0; i < 8; ++i) {
                float A   = znf[i] + bn;               // rounds at ~256 scale
                float val = A - 2.0f * acc[i][j];      // 2*acc exact; single rounding
                if (val < bestv[i] || (val == bestv[i] && kidx < besti[i])) {
                    bestv[i] = val; besti[i] = kidx;
                }
            }
        }
    }

    // ---- argmin reduce across tx (32 lanes = half-wave), lowest index on ties ----
    #pragma unroll
    for (int i = 0; i < 8; ++i) {
        float v = bestv[i]; int ix = besti[i];
        #pragma unroll
        for (int off = 16; off; off >>= 1) {
            float ov = __shfl_xor(v, off);
            int   oi = __shfl_xor(ix, off);
            if (ov < v || (ov == v && oi < ix)) { v = ov; ix = oi; }
        }
        if (tx == 0) {
            bestm[m_base + i] = ix;
            out[IDX_OFF + (size_t)blk * MT + m_base + i] = (float)ix;
        }
    }
    __syncthreads();

    // ---- epilogue: gather codebook rows (L2), write z_q coalesced, loss ----
    float lsum = 0.f;
    const size_t zq_base = (size_t)b * D_DIM * HW + p0;
    for (int i2 = t; i2 < D_DIM * MT / 4; i2 += THREADS) {
        int p = i2 & (MT - 1), d4 = i2 >> 7;
        int idx = bestm[p];
        float4 cv = *(const float4*)(cb + (size_t)idx * D_DIM + d4 * 4);
        float z0 = As[(d4 * 4 + 0) * MT + p];
        float z1 = As[(d4 * 4 + 1) * MT + p];
        float z2 = As[(d4 * 4 + 2) * MT + p];
        float z3 = As[(d4 * 4 + 3) * MT + p];
        float e0 = cv.x - z0, e1 = cv.y - z1, e2 = cv.z - z2, e3 = cv.w - z3;
        lsum = fmaf(e0, e0, lsum); lsum = fmaf(e1, e1, lsum);
        lsum = fmaf(e2, e2, lsum); lsum = fmaf(e3, e3, lsum);
        out[zq_base + (size_t)(d4 * 4 + 0) * HW + p] = cv.x;
        out[zq_base + (size_t)(d4 * 4 + 1) * HW + p] = cv.y;
        out[zq_base + (size_t)(d4 * 4 + 2) * HW + p] = cv.z;
        out[zq_base + (size_t)(d4 * 4 + 3) * HW + p] = cv.w;
    }
    #pragma unroll
    for (int off = 32; off; off >>= 1) lsum += __shfl_xor(lsum, off);
    __syncthreads();
    if ((t & 63) == 0) Es[t >> 6] = lsum;
    __syncthreads();
    if (t == 0) {
        float s = 0.f;
        #pragma unroll
        for (int w = 0; w < 8; ++w) s += Es[w];
        atomicAdd(out + LOSS_OFF, s * (1.25f / 8388608.f));
    }
}

extern "C" void kernel_launch(void* const* d_in, const int* in_sizes, int n_in,
                              void* d_out, int out_size, void* d_ws, size_t ws_size,
                              hipStream_t stream) {
    const float* z  = (const float*)d_in[0];
    const float* cb = (const float*)d_in[1];
    float* out = (float*)d_out;
    float* enorm = (float*)d_ws;

    hipMemsetAsync(out + LOSS_OFF, 0, sizeof(float), stream);

    enorm_kernel<<<256, 256, 0, stream>>>(cb, enorm);

    hipFuncSetAttribute((const void*)vq_kernel,
                        hipFuncAttributeMaxDynamicSharedMemorySize, SMEM_BYTES);
    vq_kernel<<<256, THREADS, SMEM_BYTES, stream>>>(z, cb, enorm, out);
}